// Round 9
// baseline (3685.152 us; speedup 1.0000x reference)
//
#include <hip/hip_runtime.h>
#include <math.h>

#define B_TOT 512
#define T_FR  18
#define NSTEP 16

typedef __attribute__((ext_vector_type(8))) short bf16x8;
typedef __attribute__((ext_vector_type(4))) float f32x4;

__device__ __forceinline__ float gelu_f(float x) {
    return 0.5f * x * (1.0f + erff(x * 0.70710678118654752f));
}
__device__ __forceinline__ float sigmoid_f(float x) {
    return 1.0f / (1.0f + expf(-x));
}
__device__ __forceinline__ short f2bf(float x) {
    unsigned int u = __float_as_uint(x);
    return (short)((u + 0x7FFFu + ((u >> 16) & 1u)) >> 16);
}
__device__ __forceinline__ float bflo(unsigned int u) { return __uint_as_float(u << 16); }
__device__ __forceinline__ float bfhi(unsigned int u) { return __uint_as_float(u & 0xffff0000u); }
__device__ __forceinline__ float bf2f(short s) {
    return __uint_as_float(((unsigned int)(unsigned short)s) << 16);
}
__device__ __forceinline__ bf16x8 ld_bf8(const short* p) {
    const short4 lo = *reinterpret_cast<const short4*>(p);
    const short4 hi = *reinterpret_cast<const short4*>(p + 4);
    bf16x8 r;
    r[0] = lo.x; r[1] = lo.y; r[2] = lo.z; r[3] = lo.w;
    r[4] = hi.x; r[5] = hi.y; r[6] = hi.z; r[7] = hi.w;
    return r;
}

// ---------------------------------------------------------------- init ----
__global__ __launch_bounds__(256) void init_kernel(
    const float* __restrict__ mask_w, const float* __restrict__ mask_b,
    const float* __restrict__ e2w,
    const float* __restrict__ wih, const float* __restrict__ whh,
    const float* __restrict__ qw,
    const float* __restrict__ tsw, const float* __restrict__ tsb,
    const float* __restrict__ kw, const float* __restrict__ vw,
    float* __restrict__ rmw, float* __restrict__ rmb,
    float* __restrict__ kbf, float* __restrict__ vbf,
    short* __restrict__ w2bf, short* __restrict__ wihbf, short* __restrict__ whhbf,
    short* __restrict__ qwbf, short* __restrict__ kwf, short* __restrict__ vwf)
{
    const int tid = threadIdx.x, bid = blockIdx.x;
    const int gid = bid * 256 + tid, gstr = gridDim.x * 256;
    const float rscale = 0.08838834764831845f;  // 1/sqrt(128)

    for (int i = gid; i < 128 * 2048; i += gstr) w2bf[i] = f2bf(e2w[i]);
    for (int i = gid; i < 384 * 128; i += gstr) {
        wihbf[i] = f2bf(wih[i]);
        whhbf[i] = f2bf(whh[i]);
    }
    for (int i = gid; i < 128 * 128; i += gstr) qwbf[i] = f2bf(qw[i] * rscale);

    if (bid < 128) {
        const int j = bid;
        if (tid < 128) {
            float s = 0.f;
            for (int d = 0; d < 128; ++d) s += kw[j * 128 + d] * tsw[d * 128 + tid];
            kwf[j * 128 + tid] = f2bf(s);
        } else if (tid == 128) {
            float s = 0.f;
            for (int d = 0; d < 128; ++d) s += kw[j * 128 + d] * tsb[d];
            kbf[j] = s;
        }
    } else if (bid < 256) {
        const int j = bid - 128;
        if (tid < 128) {
            float s = 0.f;
            for (int d = 0; d < 128; ++d) s += vw[j * 128 + d] * tsw[d * 128 + tid];
            vwf[j * 128 + tid] = f2bf(s);
        } else if (tid == 128) {
            float s = 0.f;
            for (int d = 0; d < 128; ++d) s += vw[j * 128 + d] * tsb[d];
            vbf[j] = s;
        }
    }
    if (bid == 256) {
        for (int i = tid; i < 2048; i += 256) {
            const int j = i >> 7, d = i & 127;
            float s = 0.f;
            for (int c = 0; c < 128; ++c) s += mask_w[(c * 16 + j) * 128 + d];
            rmw[i] = s * (1.0f / 128.0f);
        }
        for (int i = tid; i < 16; i += 256) {
            float s = 0.f;
            for (int c = 0; c < 128; ++c) s += mask_b[c * 16 + i];
            rmb[i] = s * (1.0f / 128.0f);
        }
    }
}

// ------------------------------------------------- persistent fused kernel ----
// persistent region (lane-varying data only):
#define PO_E2B   0        // 512
#define PO_BIH   512      // 1536
#define PO_BHH   2048     // 1536
#define PO_KBF   3584     // 512
#define PO_VBF   4096     // 512
#define PO_M1B   4608     // 128
#define PO_RMB   4736     // 64
#define PO_SLOTS 4800     // 4096
#define PO_SLB   8896     // 4224 -> 13120
#define SCR      13120
// scratch:
#define S_PAIR  13120     // 2048 (persists whole step)
#define S_F2T   15168     // 4224 (enc epilogue -> kk/vv)
#define S_KK    19392     // 4224 (kk/vv -> attn)
#define S_VV    23616     // 4224
#define S_X     27840     // 12288 union region
#define POOLSZ  40128

#define LDW(mat, row, kt) (*(const bf16x8*)&mat[(size_t)(row) * 128 + (kt) * 32 + g * 8])
#define MFMA(a, bb, c) __builtin_amdgcn_mfma_f32_16x16x32_bf16((a), (bb), (c), 0, 0, 0)

__global__ __launch_bounds__(512, 2) void fused_all_kernel(
    const float* __restrict__ frames,
    const short* __restrict__ w2bf,
    const float* __restrict__ e1w_g, const float* __restrict__ e1b_g,
    const float* __restrict__ e2b_g,
    const float* __restrict__ slot_mu,
    const short* __restrict__ kwf, const short* __restrict__ vwf,
    const float* __restrict__ kbf_g, const float* __restrict__ vbf_g,
    const short* __restrict__ qwbf,
    const short* __restrict__ wihbf, const short* __restrict__ whhbf,
    const float* __restrict__ bih_g, const float* __restrict__ bhh_g,
    const float* __restrict__ m1w_g, const float* __restrict__ m1b_g,
    const float* __restrict__ m2w_g, const float* __restrict__ m2b_g,
    const float* __restrict__ upw_g, const float* __restrict__ upb_g,
    const float* __restrict__ r1w_g, const float* __restrict__ r1b_g,
    const float* __restrict__ r2w_g, const float* __restrict__ r2b_g,
    const float* __restrict__ rmw_g, const float* __restrict__ rmb_g,
    float* __restrict__ out)
{
    __shared__ __align__(16) char POOL[POOLSZ];
    const int tid = threadIdx.x;
    const int lane = tid & 63, w = tid >> 6;          // 8 waves
    const int g = lane >> 4, cn = lane & 15;
    const int b = blockIdx.x;
    const int px = tid & 255, half = tid >> 8;
    const int py = px >> 4, pxx = px & 15;

    float* E2B = (float*)(POOL + PO_E2B);
    float* BIH = (float*)(POOL + PO_BIH);
    float* BHH = (float*)(POOL + PO_BHH);
    float* KBF = (float*)(POOL + PO_KBF);
    float* VBF = (float*)(POOL + PO_VBF);
    float* M1B = (float*)(POOL + PO_M1B);
    float* RMB = (float*)(POOL + PO_RMB);
    float* SLOTS = (float*)(POOL + PO_SLOTS);
    short* SLB = (short*)(POOL + PO_SLB);

    float* PAIR = (float*)(POOL + S_PAIR);
    short* F2T  = (short*)(POOL + S_F2T);
    short* KKl  = (short*)(POOL + S_KK);
    short* VVl  = (short*)(POOL + S_VV);
    short* F1S  = (short*)(POOL + S_X);
    short* QQB  = (short*)(POOL + S_X);
    short* UPDB = (short*)(POOL + S_X + 4224);
    float* ATT  = (float*)(POOL + S_X + 8448);
    float* MASKl = (float*)(POOL + S_X);
    float* M1O  = (float*)(POOL + S_X + 8192);
    float* MOT  = (float*)(POOL + S_X + 9216);
    float* MLL  = (float*)(POOL + S_X + 9280);
    float* WARP = (float*)(POOL + S_X + 9792);
    float* DIFF = (float*)(POOL + S_X + 10816);
    float* PART = (float*)(POOL + S_X);
    short* R1S  = (short*)(POOL + S_F2T);             // overlays F2T+KK in decode

    // ---------------- persistent preload ----------------
    if (tid < 128) {
        E2B[tid] = e2b_g[tid];
        KBF[tid] = kbf_g[tid]; VBF[tid] = vbf_g[tid];
        M1B[tid & 31] = m1b_g[tid & 31];              // redundant writes ok
    }
    if (tid >= 128 && tid < 512) {
        const int i = tid - 128;
        if (i < 384) { BIH[i] = bih_g[i]; BHH[i] = bhh_g[i]; }
    }
    if (tid < 16) RMB[tid] = rmb_g[tid];
    for (int i = tid; i < 1024; i += 512) {
        const float v = slot_mu[i];
        SLOTS[i] = v;
        SLB[(i >> 7) * 132 + (i & 127)] = f2bf(v);
    }
    for (int i = tid; i < 8 * 132; i += 512) SLB[8 * 132 + i] = 0;

    const int bcol = (4 * (cn >> 2) + (g & 1) * 2) * 20 + 4 * (cn & 3);
    const size_t arowbase = (size_t)(w * 16 + cn) * 2048;
    const int rowR = 16 * w + cn, rowZ = 128 + 16 * w + cn, rowN = 256 + 16 * w + cn;
    __syncthreads();

#pragma unroll 1
    for (int t = 0; t < NSTEP; ++t) {
        // ---------------- encoder ----------------
        PAIR[tid] = frames[((size_t)b * T_FR + t + 1 - half) * 256 + px];
        __syncthreads();

        float nb0[9], nb1[9];
#pragma unroll
        for (int ky = 0; ky < 3; ++ky)
#pragma unroll
        for (int kx = 0; kx < 3; ++kx) {
            const int yy = py + ky - 1, xx = pxx + kx - 1;
            const bool ok = (yy >= 0 && yy < 16 && xx >= 0 && xx < 16);
            nb0[ky * 3 + kx] = ok ? PAIR[yy * 16 + xx] : 0.f;
            nb1[ky * 3 + kx] = ok ? PAIR[256 + yy * 16 + xx] : 0.f;
        }
        f32x4 eacc = {0.f, 0.f, 0.f, 0.f};
        for (int ch = 0; ch < 8; ++ch) {               // 16-ci chunks
            const int ci0 = ch * 16 + half * 8;
#pragma unroll 4
            for (int j = 0; j < 8; ++j) {
                const int ci = ci0 + j;
                const float* wr = &e1w_g[ci * 18];     // wave-uniform -> s_load
                float a = e1b_g[ci];
#pragma unroll
                for (int q = 0; q < 9; ++q) a += nb0[q] * wr[q] + nb1[q] * wr[q + 9];
                F1S[(half * 8 + j) * 320 + py * 20 + pxx] = f2bf(gelu_f(a));
            }
            __syncthreads();
            int rb = (g >> 1) * 320 + bcol;
            int k0 = ch * 256 + g * 8;
            for (int kt = 0; kt < 8; ++kt) {
                const short4 lo = *(const short4*)&F1S[rb];
                const short4 hi = *(const short4*)&F1S[rb + 20];
                bf16x8 bfr;
                bfr[0] = lo.x; bfr[1] = lo.y; bfr[2] = lo.z; bfr[3] = lo.w;
                bfr[4] = hi.x; bfr[5] = hi.y; bfr[6] = hi.z; bfr[7] = hi.w;
                const bf16x8 a0 = *(const bf16x8*)&w2bf[arowbase + k0];
                eacc = MFMA(a0, bfr, eacc);
                rb += 640; k0 += 32;
            }
            __syncthreads();
        }
        {
            const int co0 = w * 16 + 4 * g;
            short4 s0;
            s0.x = f2bf(gelu_f(eacc[0] + E2B[co0]));
            s0.y = f2bf(gelu_f(eacc[1] + E2B[co0 + 1]));
            s0.z = f2bf(gelu_f(eacc[2] + E2B[co0 + 2]));
            s0.w = f2bf(gelu_f(eacc[3] + E2B[co0 + 3]));
            *(short4*)&F2T[cn * 132 + co0] = s0;
        }
        __syncthreads();

        // ---------------- kk/vv (fused weights streamed from L2) ----------------
        {
            bf16x8 aT[4];
#pragma unroll
            for (int kt = 0; kt < 4; ++kt)
                aT[kt] = ld_bf8(&F2T[cn * 132 + kt * 32 + g * 8]);
            const short* wf = (w >= 4) ? vwf : kwf;
            const int cb = 32 * (w & 3);
            f32x4 ac0 = {0.f, 0.f, 0.f, 0.f}, ac1 = {0.f, 0.f, 0.f, 0.f};
#pragma unroll
            for (int kt = 0; kt < 4; ++kt) {
                ac0 = MFMA(aT[kt], LDW(wf, cb + cn, kt), ac0);
                ac1 = MFMA(aT[kt], LDW(wf, cb + 16 + cn, kt), ac1);
            }
            short* dst = (w >= 4) ? VVl : KKl;
            const float* bias = (w >= 4) ? VBF : KBF;
#pragma unroll
            for (int r = 0; r < 4; ++r) {
                dst[(4 * g + r) * 132 + cb + cn] = f2bf(ac0[r] + bias[cb + cn]);
                dst[(4 * g + r) * 132 + cb + 16 + cn] = f2bf(ac1[r] + bias[cb + 16 + cn]);
            }
        }
        __syncthreads();

        // ---------------- slot attention: 3 iterations ----------------
        for (int it = 0; it < 3; ++it) {
            bf16x8 aS[4];
#pragma unroll
            for (int kt = 0; kt < 4; ++kt)
                aS[kt] = ld_bf8(&SLB[cn * 132 + kt * 32 + g * 8]);
            {
                f32x4 qa = {0.f, 0.f, 0.f, 0.f};
#pragma unroll
                for (int kt = 0; kt < 4; ++kt)
                    qa = MFMA(aS[kt], LDW(qwbf, 16 * w + cn, kt), qa);
#pragma unroll
                for (int r = 0; r < 4; ++r)
                    QQB[(4 * g + r) * 132 + 16 * w + cn] = f2bf(qa[r]);
            }
            __syncthreads();
            if (tid < 128) {
                const int kq = tid >> 4, n = tid & 15;
                float a = 0.f;
                for (int d = 0; d < 128; d += 4) {
                    const uint2 q2 = *(const uint2*)&QQB[kq * 132 + d];
                    const uint2 k2 = *(const uint2*)&KKl[n * 132 + d];
                    a += bflo(q2.x) * bflo(k2.x) + bfhi(q2.x) * bfhi(k2.x)
                       + bflo(q2.y) * bflo(k2.y) + bfhi(q2.y) * bfhi(k2.y);
                }
                ATT[kq * 16 + n] = a;
            }
            __syncthreads();
            if (tid < 16) {
                const int n = tid;
                float m = -1e30f;
#pragma unroll
                for (int kq = 0; kq < 8; ++kq) m = fmaxf(m, ATT[kq * 16 + n]);
                float e[8], ssum = 0.f;
#pragma unroll
                for (int kq = 0; kq < 8; ++kq) { e[kq] = expf(ATT[kq * 16 + n] - m); ssum += e[kq]; }
                const float inv = 1.f / ssum;
#pragma unroll
                for (int kq = 0; kq < 8; ++kq) ATT[kq * 16 + n] = e[kq] * inv;
            }
            __syncthreads();
            {
                const int k8 = tid >> 6, d0 = 2 * (tid & 63);
                float a0 = 0.f, a1 = 0.f;
#pragma unroll
                for (int n = 0; n < 16; ++n) {
                    const float at = ATT[k8 * 16 + n];
                    const unsigned int v = *(const unsigned int*)&VVl[n * 132 + d0];
                    a0 += at * bflo(v);
                    a1 += at * bfhi(v);
                }
                const unsigned int packed =
                    (unsigned int)(unsigned short)f2bf(a0) |
                    ((unsigned int)(unsigned short)f2bf(a1) << 16);
                *(unsigned int*)&UPDB[k8 * 132 + d0] = packed;
                *(unsigned int*)&UPDB[(8 + k8) * 132 + d0] = 0u;   // pad rows (region aliased)
            }
            __syncthreads();
            {
                bf16x8 aU[4];
#pragma unroll
                for (int kt = 0; kt < 4; ++kt)
                    aU[kt] = ld_bf8(&UPDB[cn * 132 + kt * 32 + g * 8]);
                f32x4 aR = {0.f, 0.f, 0.f, 0.f}, aZ = {0.f, 0.f, 0.f, 0.f};
                f32x4 aNI = {0.f, 0.f, 0.f, 0.f}, aNH = {0.f, 0.f, 0.f, 0.f};
#pragma unroll
                for (int kt = 0; kt < 4; ++kt) {
                    aR  = MFMA(aU[kt], LDW(wihbf, rowR, kt), aR);
                    aR  = MFMA(aS[kt], LDW(whhbf, rowR, kt), aR);
                    aZ  = MFMA(aU[kt], LDW(wihbf, rowZ, kt), aZ);
                    aZ  = MFMA(aS[kt], LDW(whhbf, rowZ, kt), aZ);
                    aNI = MFMA(aU[kt], LDW(wihbf, rowN, kt), aNI);
                    aNH = MFMA(aS[kt], LDW(whhbf, rowN, kt), aNH);
                }
                if (g < 2) {
                    const int colj = 16 * w + cn;
                    const float br = BIH[colj] + BHH[colj];
                    const float bz = BIH[128 + colj] + BHH[128 + colj];
                    const float bi = BIH[256 + colj], bh = BHH[256 + colj];
#pragma unroll
                    for (int r = 0; r < 4; ++r) {
                        const int kq = 4 * g + r;
                        const float rr = sigmoid_f(aR[r] + br);
                        const float zz = sigmoid_f(aZ[r] + bz);
                        const float nn = tanhf(aNI[r] + bi + rr * (aNH[r] + bh));
                        const float hold = SLOTS[kq * 128 + colj];
                        const float hv = (1.f - zz) * nn + zz * hold;
                        SLOTS[kq * 128 + colj] = hv;
                        SLB[kq * 132 + colj] = f2bf(hv);
                    }
                }
            }
            __syncthreads();
        }

        // ---------------- decode ----------------
        if (tid < 256) {
            const int kq = tid >> 5, c = tid & 31;
            float a = M1B[c];
            for (int d = 0; d < 128; d += 4) {
                const uint2 s2 = *(const uint2*)&SLB[kq * 132 + d];
                const float4 w4 = *(const float4*)&m1w_g[c * 128 + d];
                a += w4.x * bflo(s2.x) + w4.y * bfhi(s2.x)
                   + w4.z * bflo(s2.y) + w4.w * bfhi(s2.y);
            }
            M1O[kq * 32 + c] = gelu_f(a);
        } else if (tid < 384) {
            const int q = tid - 256, kq = q >> 4, j = q & 15;
            float a = RMB[j];
            for (int d = 0; d < 128; d += 4) {
                const uint2 s2 = *(const uint2*)&SLB[kq * 132 + d];
                const float4 w4 = *(const float4*)&rmw_g[j * 128 + d];
                a += w4.x * bflo(s2.x) + w4.y * bfhi(s2.x)
                   + w4.z * bflo(s2.y) + w4.w * bfhi(s2.y);
            }
            MLL[kq * 16 + j] = a;
        }
        __syncthreads();
        if (tid < 16) {
            const int kq = tid >> 1, e = tid & 1;
            float a = m2b_g[e];
#pragma unroll
            for (int c = 0; c < 32; ++c) a += M1O[kq * 32 + c] * m2w_g[e * 32 + c];
            MOT[kq * 2 + e] = tanhf(a) * 4.0f;
        }
        {
            const int jj = (py >> 2) * 4 + (pxx >> 2);
            const int wq = (py & 3) * 4 + (pxx & 3);
#pragma unroll
            for (int k2 = 0; k2 < 4; ++k2) {
                const int ko = half * 4 + k2;
                float a = upb_g[ko];
#pragma unroll
                for (int i8 = 0; i8 < 8; ++i8)
                    a += MLL[i8 * 16 + jj] * upw_g[(i8 * 8 + ko) * 16 + wq];
                MASKl[ko * 256 + px] = a;
            }
        }
        __syncthreads();
        if (tid < 256) {
            float m = -1e30f;
#pragma unroll
            for (int kq = 0; kq < 8; ++kq) m = fmaxf(m, MASKl[kq * 256 + px]);
            float e[8], ssum = 0.f;
#pragma unroll
            for (int kq = 0; kq < 8; ++kq) { e[kq] = expf(MASKl[kq * 256 + px] - m); ssum += e[kq]; }
            const float inv = 1.f / ssum;
            const float gxv = -1.0f + (2.0f / 15.0f) * pxx;
            const float gyv = -1.0f + (2.0f / 15.0f) * py;
            float wsum = 0.f;
#pragma unroll
            for (int kq = 0; kq < 8; ++kq) {
                const float fx = MOT[kq * 2 + 0] * 0.125f;
                const float fy = MOT[kq * 2 + 1] * 0.125f;
                const float sgx = fminf(fmaxf(gxv + fx, -1.f), 1.f);
                const float sgy = fminf(fmaxf(gyv + fy, -1.f), 1.f);
                const float ix = (sgx + 1.f) * 7.5f;
                const float iy = (sgy + 1.f) * 7.5f;
                const float x0f = floorf(ix), y0f = floorf(iy);
                const float wx = ix - x0f, wy = iy - y0f;
                const int x0 = (int)x0f, y0 = (int)y0f;
                const int x1 = min(x0 + 1, 15), y1 = min(y0 + 1, 15);
                const float v00 = PAIR[y0 * 16 + x0], v01 = PAIR[y0 * 16 + x1];
                const float v10 = PAIR[y1 * 16 + x0], v11 = PAIR[y1 * 16 + x1];
                const float val = (1.f - wy) * ((1.f - wx) * v00 + wx * v01) +
                                  wy * ((1.f - wx) * v10 + wx * v11);
                wsum += (e[kq] * inv) * val;
            }
            WARP[px] = wsum;
            DIFF[px] = wsum - PAIR[px];
        }
        __syncthreads();
        float nbz[9];
#pragma unroll
        for (int ky = 0; ky < 3; ++ky)
#pragma unroll
        for (int kx = 0; kx < 3; ++kx) {
            const int y2 = py + ky - 1, x2 = pxx + kx - 1;
            const bool ok = (y2 >= 0 && y2 < 16 && x2 >= 0 && x2 < 16);
            nbz[ky * 3 + kx] = ok ? DIFF[y2 * 16 + x2] : 0.f;
        }
        float racc = 0.f;
        for (int c0 = 0; c0 < 64; c0 += 16) {
#pragma unroll 4
            for (int cl = 0; cl < 8; ++cl) {
                const int c = c0 + half * 8 + cl;
                float a = r1b_g[c];
#pragma unroll
                for (int q = 0; q < 9; ++q) a += nbz[q] * r1w_g[c * 9 + q];
                R1S[(half * 8 + cl) * 264 + px] = f2bf(gelu_f(a));
            }
            __syncthreads();
#pragma unroll 4
            for (int cl = 0; cl < 8; ++cl) {
                const int c = c0 + half * 8 + cl;
                const float* r2r = &r2w_g[c * 9];
#pragma unroll
                for (int ky = 0; ky < 3; ++ky)
#pragma unroll
                for (int kx = 0; kx < 3; ++kx) {
                    const int y2 = py + ky - 1, x2 = pxx + kx - 1;
                    if (y2 >= 0 && y2 < 16 && x2 >= 0 && x2 < 16)
                        racc += bf2f(R1S[(half * 8 + cl) * 264 + y2 * 16 + x2]) * r2r[ky * 3 + kx];
                }
            }
            __syncthreads();
        }
        PART[tid] = racc;
        __syncthreads();
        if (tid < 256) {
            const float rtot = PART[px] + PART[256 + px];
            const float resv = tanhf(rtot + r2b_g[0]) * 0.1f;
            const float pred = fminf(fmaxf(WARP[px] + resv, 0.f), 1.f);
            out[((size_t)b * NSTEP + t) * 256 + px] = pred;
        }
        __syncthreads();
    }
}

// -------------------------------------------------------------- launch ----
extern "C" void kernel_launch(void* const* d_in, const int* in_sizes, int n_in,
                              void* d_out, int out_size, void* d_ws, size_t ws_size,
                              hipStream_t stream)
{
    const float* frames = (const float*)d_in[0];
    const float* e1w = (const float*)d_in[1];
    const float* e1b = (const float*)d_in[2];
    const float* e2w = (const float*)d_in[3];
    const float* e2b = (const float*)d_in[4];
    const float* slot_mu = (const float*)d_in[5];
    const float* tsw = (const float*)d_in[6];
    const float* tsb = (const float*)d_in[7];
    const float* qw = (const float*)d_in[8];
    const float* kw = (const float*)d_in[9];
    const float* vw = (const float*)d_in[10];
    const float* wih = (const float*)d_in[11];
    const float* whh = (const float*)d_in[12];
    const float* bih = (const float*)d_in[13];
    const float* bhh = (const float*)d_in[14];
    const float* m1w = (const float*)d_in[15];
    const float* m1b = (const float*)d_in[16];
    const float* m2w = (const float*)d_in[17];
    const float* m2b = (const float*)d_in[18];
    const float* maskw = (const float*)d_in[19];
    const float* maskb = (const float*)d_in[20];
    const float* upw = (const float*)d_in[21];
    const float* upb = (const float*)d_in[22];
    const float* r1w = (const float*)d_in[23];
    const float* r1b = (const float*)d_in[24];
    const float* r2w = (const float*)d_in[25];
    const float* r2b = (const float*)d_in[26];

    float* ws = (float*)d_ws;
    float* rmw  = ws + 0;
    float* rmb  = ws + 2048;
    float* kbf  = ws + 2064;
    float* vbf  = ws + 2192;
    short* w2bf  = (short*)(ws + 2320);
    short* wihbf = (short*)(ws + 133392);
    short* whhbf = (short*)(ws + 157968);
    short* qwbf  = (short*)(ws + 182544);
    short* kwf   = (short*)(ws + 190736);
    short* vwf   = (short*)(ws + 198928);

    hipLaunchKernelGGL(init_kernel, dim3(512), dim3(256), 0, stream,
                       maskw, maskb, e2w, wih, whh, qw, tsw, tsb, kw, vw,
                       rmw, rmb, kbf, vbf, w2bf, wihbf, whhbf, qwbf, kwf, vwf);
    hipLaunchKernelGGL(fused_all_kernel, dim3(512), dim3(512), 0, stream,
                       frames, w2bf, e1w, e1b, e2b, slot_mu,
                       kwf, vwf, kbf, vbf, qwbf, wihbf, whhbf, bih, bhh,
                       m1w, m1b, m2w, m2b, upw, upb,
                       r1w, r1b, r2w, r2b, rmw, rmb,
                       (float*)d_out);
}

// Round 10
// 2119.849 us; speedup vs baseline: 1.7384x; 1.7384x over previous
//
#include <hip/hip_runtime.h>
#include <math.h>

#define B_TOT 512
#define T_FR  18
#define NSTEP 16

typedef __attribute__((ext_vector_type(8))) short bf16x8;
typedef __attribute__((ext_vector_type(4))) float f32x4;

__device__ __forceinline__ float gelu_f(float x) {
    return 0.5f * x * (1.0f + erff(x * 0.70710678118654752f));
}
__device__ __forceinline__ float sigmoid_f(float x) {
    return 1.0f / (1.0f + expf(-x));
}
__device__ __forceinline__ short f2bf(float x) {
    unsigned int u = __float_as_uint(x);
    return (short)((u + 0x7FFFu + ((u >> 16) & 1u)) >> 16);
}
__device__ __forceinline__ float bflo(unsigned int u) { return __uint_as_float(u << 16); }
__device__ __forceinline__ float bfhi(unsigned int u) { return __uint_as_float(u & 0xffff0000u); }
__device__ __forceinline__ float bf2f(short s) {
    return __uint_as_float(((unsigned int)(unsigned short)s) << 16);
}
__device__ __forceinline__ bf16x8 ld_bf8(const short* p) {
    const short4 lo = *reinterpret_cast<const short4*>(p);
    const short4 hi = *reinterpret_cast<const short4*>(p + 4);
    bf16x8 r;
    r[0] = lo.x; r[1] = lo.y; r[2] = lo.z; r[3] = lo.w;
    r[4] = hi.x; r[5] = hi.y; r[6] = hi.z; r[7] = hi.w;
    return r;
}

// ---------------------------------------------------------------- init ----
__global__ __launch_bounds__(256) void init_kernel(
    const float* __restrict__ mask_w, const float* __restrict__ mask_b,
    const float* __restrict__ e2w,
    const float* __restrict__ wih, const float* __restrict__ whh,
    const float* __restrict__ qw,
    const float* __restrict__ tsw, const float* __restrict__ tsb,
    const float* __restrict__ kw, const float* __restrict__ vw,
    float* __restrict__ rmw, float* __restrict__ rmb,
    float* __restrict__ kbf, float* __restrict__ vbf,
    short* __restrict__ w2bf, short* __restrict__ wihbf, short* __restrict__ whhbf,
    short* __restrict__ qwbf, short* __restrict__ kwf, short* __restrict__ vwf)
{
    const int tid = threadIdx.x, bid = blockIdx.x;
    const int gid = bid * 256 + tid, gstr = gridDim.x * 256;
    const float rscale = 0.08838834764831845f;  // 1/sqrt(128)

    for (int i = gid; i < 128 * 2048; i += gstr) w2bf[i] = f2bf(e2w[i]);
    for (int i = gid; i < 384 * 128; i += gstr) {
        wihbf[i] = f2bf(wih[i]);
        whhbf[i] = f2bf(whh[i]);
    }
    for (int i = gid; i < 128 * 128; i += gstr) qwbf[i] = f2bf(qw[i] * rscale);

    if (bid < 128) {
        const int j = bid;
        if (tid < 128) {
            float s = 0.f;
            for (int d = 0; d < 128; ++d) s += kw[j * 128 + d] * tsw[d * 128 + tid];
            kwf[j * 128 + tid] = f2bf(s);
        } else if (tid == 128) {
            float s = 0.f;
            for (int d = 0; d < 128; ++d) s += kw[j * 128 + d] * tsb[d];
            kbf[j] = s;
        }
    } else if (bid < 256) {
        const int j = bid - 128;
        if (tid < 128) {
            float s = 0.f;
            for (int d = 0; d < 128; ++d) s += vw[j * 128 + d] * tsw[d * 128 + tid];
            vwf[j * 128 + tid] = f2bf(s);
        } else if (tid == 128) {
            float s = 0.f;
            for (int d = 0; d < 128; ++d) s += vw[j * 128 + d] * tsb[d];
            vbf[j] = s;
        }
    }
    if (bid == 256) {
        for (int i = tid; i < 2048; i += 256) {
            const int j = i >> 7, d = i & 127;
            float s = 0.f;
            for (int c = 0; c < 128; ++c) s += mask_w[(c * 16 + j) * 128 + d];
            rmw[i] = s * (1.0f / 128.0f);
        }
        for (int i = tid; i < 16; i += 256) {
            float s = 0.f;
            for (int c = 0; c < 128; ++c) s += mask_b[c * 16 + i];
            rmb[i] = s * (1.0f / 128.0f);
        }
    }
}

// ------------------------------------------------- persistent fused kernel ----
// R5 layout, M1W/RMW padded to 132-short rows (bank-conflict fix)
#define PO_E1W   0
#define PO_E1B   9216
#define PO_E2B   9728
#define PO_BIH   10240
#define PO_BHH   11776
#define PO_KBF   13312
#define PO_VBF   13824
#define PO_M1B   14336
#define PO_M2W   14464
#define PO_M2B   14720
#define PO_UPB   14736
#define PO_RMB   14768
#define PO_R2B   14832
#define PO_UPW   14848
#define PO_R1W   18944
#define PO_R1B   21248
#define PO_R2W   21504
#define PO_M1W   23808     // 32 x 132 shorts = 8448
#define PO_RMW   32256     // 16 x 132 shorts = 4224
#define PO_SLOTS 36480     // 4096
#define PO_SLB   40576     // 4224
#define SCR      44800
// scratch (relative to SCR):
#define S_PAIR 0
#define S_F1S  2048
#define S_F2T  22528
#define S_KK   0
#define S_VV   4224
#define S_QQ   8448
#define S_UPD  12672
#define S_ATT  16896
#define S_MASK 0
#define S_IMG  8192
#define S_WARP 9216
#define S_DIFF 10240
#define S_M1O  11264
#define S_MOT  12288
#define S_MLL  12352
#define S_R1S  12864
#define POOLSZ (44800 + 29824)

#define LDW(mat, row, kt) (*(const bf16x8*)&mat[(size_t)(row) * 128 + (kt) * 32 + g * 8])
#define MFMA(a, bb, c) __builtin_amdgcn_mfma_f32_16x16x32_bf16((a), (bb), (c), 0, 0, 0)

__global__ __launch_bounds__(256, 2) void fused_all_kernel(
    const float* __restrict__ frames,
    const short* __restrict__ w2bf,
    const float* __restrict__ e1w_g, const float* __restrict__ e1b_g,
    const float* __restrict__ e2b_g,
    const float* __restrict__ slot_mu,
    const short* __restrict__ kwf, const short* __restrict__ vwf,
    const float* __restrict__ kbf_g, const float* __restrict__ vbf_g,
    const short* __restrict__ qwbf,
    const short* __restrict__ wihbf, const short* __restrict__ whhbf,
    const float* __restrict__ bih_g, const float* __restrict__ bhh_g,
    const float* __restrict__ m1w_g, const float* __restrict__ m1b_g,
    const float* __restrict__ m2w_g, const float* __restrict__ m2b_g,
    const float* __restrict__ upw_g, const float* __restrict__ upb_g,
    const float* __restrict__ r1w_g, const float* __restrict__ r1b_g,
    const float* __restrict__ r2w_g, const float* __restrict__ r2b_g,
    const float* __restrict__ rmw_g, const float* __restrict__ rmb_g,
    float* __restrict__ out)
{
    __shared__ __align__(16) char POOL[POOLSZ];
    const int tid = threadIdx.x;
    const int lane = tid & 63, w = tid >> 6;          // 4 waves
    const int g = lane >> 4, cn = lane & 15;
    const int b = blockIdx.x;

    float* E1W = (float*)(POOL + PO_E1W);
    float* E1B = (float*)(POOL + PO_E1B);
    float* E2B = (float*)(POOL + PO_E2B);
    float* BIH = (float*)(POOL + PO_BIH);
    float* BHH = (float*)(POOL + PO_BHH);
    float* KBF = (float*)(POOL + PO_KBF);
    float* VBF = (float*)(POOL + PO_VBF);
    float* M1B = (float*)(POOL + PO_M1B);
    float* M2W = (float*)(POOL + PO_M2W);
    float* M2B = (float*)(POOL + PO_M2B);
    float* UPB = (float*)(POOL + PO_UPB);
    float* RMB = (float*)(POOL + PO_RMB);
    float* R2B = (float*)(POOL + PO_R2B);
    float* UPW = (float*)(POOL + PO_UPW);
    float* R1W = (float*)(POOL + PO_R1W);
    float* R1B = (float*)(POOL + PO_R1B);
    float* R2W = (float*)(POOL + PO_R2W);
    short* M1W = (short*)(POOL + PO_M1W);
    short* RMW = (short*)(POOL + PO_RMW);
    float* SLOTS = (float*)(POOL + PO_SLOTS);
    short* SLB = (short*)(POOL + PO_SLB);

    float* PAIR = (float*)(POOL + SCR + S_PAIR);
    short* F1S  = (short*)(POOL + SCR + S_F1S);
    short* F2T  = (short*)(POOL + SCR + S_F2T);
    short* KKl  = (short*)(POOL + SCR + S_KK);
    short* VVl  = (short*)(POOL + SCR + S_VV);
    short* QQB  = (short*)(POOL + SCR + S_QQ);
    short* UPDB = (short*)(POOL + SCR + S_UPD);
    float* ATT  = (float*)(POOL + SCR + S_ATT);
    float* MASKl = (float*)(POOL + SCR + S_MASK);
    float* IMG  = (float*)(POOL + SCR + S_IMG);
    float* WARP = (float*)(POOL + SCR + S_WARP);
    float* DIFF = (float*)(POOL + SCR + S_DIFF);
    float* M1O  = (float*)(POOL + SCR + S_M1O);
    float* MOT  = (float*)(POOL + SCR + S_MOT);
    float* MLL  = (float*)(POOL + SCR + S_MLL);
    short* R1S  = (short*)(POOL + SCR + S_R1S);

    // ---------------- persistent preload ----------------
    for (int i = tid; i < 2304; i += 256) E1W[i] = e1w_g[i];
    if (tid < 128) {
        E1B[tid] = e1b_g[tid]; E2B[tid] = e2b_g[tid];
        KBF[tid] = kbf_g[tid]; VBF[tid] = vbf_g[tid];
    }
    for (int i = tid; i < 384; i += 256) { BIH[i] = bih_g[i]; BHH[i] = bhh_g[i]; }
    if (tid < 32) M1B[tid] = m1b_g[tid];
    if (tid < 64) { M2W[tid] = m2w_g[tid]; R1B[tid] = r1b_g[tid]; }
    if (tid < 2) M2B[tid] = m2b_g[tid];
    if (tid < 8) UPB[tid] = upb_g[tid];
    if (tid < 16) RMB[tid] = rmb_g[tid];
    if (tid == 0) R2B[0] = r2b_g[0];
    for (int i = tid; i < 1024; i += 256) UPW[i] = upw_g[i];
    for (int i = tid; i < 576; i += 256) { R1W[i] = r1w_g[i]; R2W[i] = r2w_g[i]; }
    for (int i = tid; i < 4096; i += 256)
        M1W[(i >> 7) * 132 + (i & 127)] = f2bf(m1w_g[i]);
    for (int i = tid; i < 2048; i += 256)
        RMW[(i >> 7) * 132 + (i & 127)] = f2bf(rmw_g[i]);
    for (int i = tid; i < 1024; i += 256) {
        const float v = slot_mu[i];
        SLOTS[i] = v;
        SLB[(i >> 7) * 132 + (i & 127)] = f2bf(v);
    }
    for (int i = tid; i < 8 * 132; i += 256) SLB[8 * 132 + i] = 0;

    const int col0 = 32 * w;
    const int py = tid >> 4, pxx = tid & 15;          // pixel for conv phases
    const int arow = (2 * w) * 16 + cn;               // enc2 A row
    const int bcol = (4 * (cn >> 2) + (g & 1) * 2) * 20 + 4 * (cn & 3);
    __syncthreads();

#pragma unroll 1
    for (int t = 0; t < NSTEP; ++t) {
        // ---------------- encoder ----------------
        PAIR[tid]       = frames[((size_t)b * T_FR + t + 1) * 256 + tid];
        PAIR[256 + tid] = frames[((size_t)b * T_FR + t) * 256 + tid];
        __syncthreads();

        float nb0[9], nb1[9];
#pragma unroll
        for (int ky = 0; ky < 3; ++ky)
#pragma unroll
        for (int kx = 0; kx < 3; ++kx) {
            const int yy = py + ky - 1, xx = pxx + kx - 1;
            const bool ok = (yy >= 0 && yy < 16 && xx >= 0 && xx < 16);
            nb0[ky * 3 + kx] = ok ? PAIR[yy * 16 + xx] : 0.f;
            nb1[ky * 3 + kx] = ok ? PAIR[256 + yy * 16 + xx] : 0.f;
        }
        f32x4 acc0 = {0.f, 0.f, 0.f, 0.f};
        f32x4 acc1 = {0.f, 0.f, 0.f, 0.f};
        for (int ch = 0; ch < 4; ++ch) {
            const int ci0 = ch * 32;
#pragma unroll 4
            for (int j = 0; j < 32; ++j) {
                const float* wr = &E1W[(ci0 + j) * 18];
                float a = E1B[ci0 + j];
#pragma unroll
                for (int q = 0; q < 9; ++q) a += nb0[q] * wr[q] + nb1[q] * wr[q + 9];
                F1S[j * 320 + py * 20 + pxx] = f2bf(gelu_f(a));
            }
            __syncthreads();
            int rb = (g >> 1) * 320 + bcol;
            int k0 = ch * 512 + g * 8;
            for (int kt = 0; kt < 16; ++kt) {
                const short4 lo = *(const short4*)&F1S[rb];
                const short4 hi = *(const short4*)&F1S[rb + 20];
                bf16x8 bfr;
                bfr[0] = lo.x; bfr[1] = lo.y; bfr[2] = lo.z; bfr[3] = lo.w;
                bfr[4] = hi.x; bfr[5] = hi.y; bfr[6] = hi.z; bfr[7] = hi.w;
                const bf16x8 a0 = *(const bf16x8*)&w2bf[(size_t)arow * 2048 + k0];
                const bf16x8 a1 = *(const bf16x8*)&w2bf[(size_t)(arow + 16) * 2048 + k0];
                acc0 = MFMA(a0, bfr, acc0);
                acc1 = MFMA(a1, bfr, acc1);
                rb += 640; k0 += 32;
            }
            __syncthreads();
        }
        {
            const int cob0 = (2 * w) * 16 + g * 4;
            short4 s0, s1;
            s0.x = f2bf(gelu_f(acc0[0] + E2B[cob0]));
            s0.y = f2bf(gelu_f(acc0[1] + E2B[cob0 + 1]));
            s0.z = f2bf(gelu_f(acc0[2] + E2B[cob0 + 2]));
            s0.w = f2bf(gelu_f(acc0[3] + E2B[cob0 + 3]));
            s1.x = f2bf(gelu_f(acc1[0] + E2B[cob0 + 16]));
            s1.y = f2bf(gelu_f(acc1[1] + E2B[cob0 + 17]));
            s1.z = f2bf(gelu_f(acc1[2] + E2B[cob0 + 18]));
            s1.w = f2bf(gelu_f(acc1[3] + E2B[cob0 + 19]));
            *(short4*)&F2T[cn * 132 + cob0] = s0;
            *(short4*)&F2T[cn * 132 + cob0 + 16] = s1;
        }
        __syncthreads();

        // ---------------- kk/vv (MFMA, fused weights streamed) ----------------
        {
            bf16x8 aT[4];
#pragma unroll
            for (int kt = 0; kt < 4; ++kt)
                aT[kt] = ld_bf8(&F2T[cn * 132 + kt * 32 + g * 8]);
            const short* wf = (w >> 1) ? vwf : kwf;
            const int h2 = w & 1;
            f32x4 ac[4];
#pragma unroll
            for (int nt = 0; nt < 4; ++nt) ac[nt] = (f32x4){0.f, 0.f, 0.f, 0.f};
#pragma unroll
            for (int kt = 0; kt < 4; ++kt)
#pragma unroll
            for (int nt = 0; nt < 4; ++nt)
                ac[nt] = MFMA(aT[kt], LDW(wf, h2 * 64 + nt * 16 + cn, kt), ac[nt]);
            short* dst = (w >> 1) ? VVl : KKl;
            const float* bias = (w >> 1) ? VBF : KBF;
#pragma unroll
            for (int nt = 0; nt < 4; ++nt) {
                const int j = h2 * 64 + nt * 16 + cn;
                const float bb = bias[j];
#pragma unroll
                for (int r = 0; r < 4; ++r)
                    dst[(4 * g + r) * 132 + j] = f2bf(ac[nt][r] + bb);
            }
        }
        __syncthreads();

        // ---------------- slot attention: 3 iterations ----------------
        for (int it = 0; it < 3; ++it) {
            bf16x8 aS[4];
#pragma unroll
            for (int kt = 0; kt < 4; ++kt)
                aS[kt] = ld_bf8(&SLB[cn * 132 + kt * 32 + g * 8]);
            {
                f32x4 qa[2] = {{0.f, 0.f, 0.f, 0.f}, {0.f, 0.f, 0.f, 0.f}};
#pragma unroll
                for (int kt = 0; kt < 4; ++kt)
#pragma unroll
                for (int nt = 0; nt < 2; ++nt)
                    qa[nt] = MFMA(aS[kt], LDW(qwbf, col0 + nt * 16 + cn, kt), qa[nt]);
#pragma unroll
                for (int nt = 0; nt < 2; ++nt)
#pragma unroll
                for (int r = 0; r < 4; ++r)
                    QQB[(4 * g + r) * 132 + col0 + nt * 16 + cn] = f2bf(qa[nt][r]);
            }
            __syncthreads();
            if (tid < 128) {
                const int kq = tid >> 4, n = tid & 15;
                float a = 0.f;
                for (int d = 0; d < 128; d += 4) {
                    const uint2 q2 = *(const uint2*)&QQB[kq * 132 + d];
                    const uint2 k2 = *(const uint2*)&KKl[n * 132 + d];
                    a += bflo(q2.x) * bflo(k2.x) + bfhi(q2.x) * bfhi(k2.x)
                       + bflo(q2.y) * bflo(k2.y) + bfhi(q2.y) * bfhi(k2.y);
                }
                ATT[kq * 16 + n] = a;
            }
            __syncthreads();
            if (tid < 16) {
                const int n = tid;
                float m = -1e30f;
#pragma unroll
                for (int kq = 0; kq < 8; ++kq) m = fmaxf(m, ATT[kq * 16 + n]);
                float e[8], ssum = 0.f;
#pragma unroll
                for (int kq = 0; kq < 8; ++kq) { e[kq] = expf(ATT[kq * 16 + n] - m); ssum += e[kq]; }
                const float inv = 1.f / ssum;
#pragma unroll
                for (int kq = 0; kq < 8; ++kq) ATT[kq * 16 + n] = e[kq] * inv;
            }
            __syncthreads();
            {
                const int k8 = tid >> 5, lg = tid & 31;
                float a0 = 0.f, a1 = 0.f, a2 = 0.f, a3 = 0.f;
#pragma unroll
                for (int n = 0; n < 16; ++n) {
                    const float at = ATT[k8 * 16 + n];
                    const uint2 v2 = *(const uint2*)&VVl[n * 132 + 4 * lg];
                    a0 += at * bflo(v2.x); a1 += at * bfhi(v2.x);
                    a2 += at * bflo(v2.y); a3 += at * bfhi(v2.y);
                }
                short4 sv;
                sv.x = f2bf(a0); sv.y = f2bf(a1); sv.z = f2bf(a2); sv.w = f2bf(a3);
                *(short4*)&UPDB[k8 * 132 + 4 * lg] = sv;
            }
            __syncthreads();
            {
                bf16x8 aU[4];
#pragma unroll
                for (int kt = 0; kt < 4; ++kt)
                    aU[kt] = ld_bf8(&UPDB[cn * 132 + kt * 32 + g * 8]);
                f32x4 aR[2], aZ[2], aNIv[2], aNHv[2];
#pragma unroll
                for (int nt = 0; nt < 2; ++nt) {
                    aR[nt] = (f32x4){0.f, 0.f, 0.f, 0.f};
                    aZ[nt] = (f32x4){0.f, 0.f, 0.f, 0.f};
                    aNIv[nt] = (f32x4){0.f, 0.f, 0.f, 0.f};
                    aNHv[nt] = (f32x4){0.f, 0.f, 0.f, 0.f};
                }
#pragma unroll
                for (int nt = 0; nt < 2; ++nt) {
                    const int colj = col0 + nt * 16 + cn;
#pragma unroll
                    for (int kt = 0; kt < 4; ++kt) {
                        aR[nt]   = MFMA(aU[kt], LDW(wihbf, colj, kt), aR[nt]);
                        aR[nt]   = MFMA(aS[kt], LDW(whhbf, colj, kt), aR[nt]);
                        aZ[nt]   = MFMA(aU[kt], LDW(wihbf, 128 + colj, kt), aZ[nt]);
                        aZ[nt]   = MFMA(aS[kt], LDW(whhbf, 128 + colj, kt), aZ[nt]);
                        aNIv[nt] = MFMA(aU[kt], LDW(wihbf, 256 + colj, kt), aNIv[nt]);
                        aNHv[nt] = MFMA(aS[kt], LDW(whhbf, 256 + colj, kt), aNHv[nt]);
                    }
                }
                __syncthreads();   // A-frag reads done before SLB rewrite
                if (g < 2) {
#pragma unroll
                    for (int nt = 0; nt < 2; ++nt) {
                        const int colj = col0 + nt * 16 + cn;
                        const float br = BIH[colj] + BHH[colj];
                        const float bz = BIH[128 + colj] + BHH[128 + colj];
                        const float bi = BIH[256 + colj], bh = BHH[256 + colj];
#pragma unroll
                        for (int r = 0; r < 4; ++r) {
                            const int kq = 4 * g + r;
                            const float rr = sigmoid_f(aR[nt][r] + br);
                            const float zz = sigmoid_f(aZ[nt][r] + bz);
                            const float nn = tanhf(aNIv[nt][r] + bi + rr * (aNHv[nt][r] + bh));
                            const float hold = SLOTS[kq * 128 + colj];
                            const float hv = (1.f - zz) * nn + zz * hold;
                            SLOTS[kq * 128 + colj] = hv;
                            SLB[kq * 132 + colj] = f2bf(hv);
                        }
                    }
                }
                __syncthreads();
            }
        }

        // ---------------- decode ----------------
        IMG[tid] = frames[((size_t)b * T_FR + t + 1) * 256 + tid];
        {
            const int kq = tid >> 5, c = tid & 31;
            float a = M1B[c];
            for (int d = 0; d < 128; d += 4) {
                const uint2 s2 = *(const uint2*)&SLB[kq * 132 + d];
                const uint2 w2 = *(const uint2*)&M1W[c * 132 + d];
                a += bflo(s2.x) * bflo(w2.x) + bfhi(s2.x) * bfhi(w2.x)
                   + bflo(s2.y) * bflo(w2.y) + bfhi(s2.y) * bfhi(w2.y);
            }
            M1O[kq * 32 + c] = gelu_f(a);
        }
        if (tid < 128) {
            const int kq = tid >> 4, j = tid & 15;
            float a = RMB[j];
            for (int d = 0; d < 128; d += 4) {
                const uint2 s2 = *(const uint2*)&SLB[kq * 132 + d];
                const uint2 w2 = *(const uint2*)&RMW[j * 132 + d];
                a += bflo(s2.x) * bflo(w2.x) + bfhi(s2.x) * bfhi(w2.x)
                   + bflo(s2.y) * bflo(w2.y) + bfhi(s2.y) * bfhi(w2.y);
            }
            MLL[kq * 16 + j] = a;
        }
        __syncthreads();
        if (tid < 16) {
            const int kq = tid >> 1, e = tid & 1;
            float a = M2B[e];
#pragma unroll
            for (int c = 0; c < 32; ++c) a += M1O[kq * 32 + c] * M2W[e * 32 + c];
            MOT[kq * 2 + e] = tanhf(a) * 4.0f;
        }
        {
            const int jj = (py >> 2) * 4 + (pxx >> 2);
            const int wq = (py & 3) * 4 + (pxx & 3);
#pragma unroll
            for (int ko = 0; ko < 8; ++ko) {
                float a = UPB[ko];
#pragma unroll
                for (int i8 = 0; i8 < 8; ++i8)
                    a += MLL[i8 * 16 + jj] * UPW[(i8 * 8 + ko) * 16 + wq];
                MASKl[ko * 256 + tid] = a;
            }
        }
        __syncthreads();
        {
            float m = -1e30f;
#pragma unroll
            for (int kq = 0; kq < 8; ++kq) m = fmaxf(m, MASKl[kq * 256 + tid]);
            float e[8], ssum = 0.f;
#pragma unroll
            for (int kq = 0; kq < 8; ++kq) { e[kq] = expf(MASKl[kq * 256 + tid] - m); ssum += e[kq]; }
            const float inv = 1.f / ssum;
            const float gxv = -1.0f + (2.0f / 15.0f) * pxx;
            const float gyv = -1.0f + (2.0f / 15.0f) * py;
            float wsum = 0.f;
#pragma unroll
            for (int kq = 0; kq < 8; ++kq) {
                const float fx = MOT[kq * 2 + 0] * 0.125f;
                const float fy = MOT[kq * 2 + 1] * 0.125f;
                const float sgx = fminf(fmaxf(gxv + fx, -1.f), 1.f);
                const float sgy = fminf(fmaxf(gyv + fy, -1.f), 1.f);
                const float ix = (sgx + 1.f) * 7.5f;
                const float iy = (sgy + 1.f) * 7.5f;
                const float x0f = floorf(ix), y0f = floorf(iy);
                const float wx = ix - x0f, wy = iy - y0f;
                const int x0 = (int)x0f, y0 = (int)y0f;
                const int x1 = min(x0 + 1, 15), y1 = min(y0 + 1, 15);
                const float v00 = IMG[y0 * 16 + x0], v01 = IMG[y0 * 16 + x1];
                const float v10 = IMG[y1 * 16 + x0], v11 = IMG[y1 * 16 + x1];
                const float val = (1.f - wy) * ((1.f - wx) * v00 + wx * v01) +
                                  wy * ((1.f - wx) * v10 + wx * v11);
                wsum += (e[kq] * inv) * val;
            }
            WARP[tid] = wsum;
            DIFF[tid] = wsum - IMG[tid];
        }
        __syncthreads();
        float nbz[9];
#pragma unroll
        for (int ky = 0; ky < 3; ++ky)
#pragma unroll
        for (int kx = 0; kx < 3; ++kx) {
            const int y2 = py + ky - 1, x2 = pxx + kx - 1;
            const bool ok = (y2 >= 0 && y2 < 16 && x2 >= 0 && x2 < 16);
            nbz[ky * 3 + kx] = ok ? DIFF[y2 * 16 + x2] : 0.f;
        }
        float racc = 0.f;
        for (int c0 = 0; c0 < 64; c0 += 32) {
#pragma unroll 4
            for (int cl = 0; cl < 32; ++cl) {
                const int c = c0 + cl;
                float a = R1B[c];
#pragma unroll
                for (int q = 0; q < 9; ++q) a += nbz[q] * R1W[c * 9 + q];
                R1S[cl * 264 + tid] = f2bf(gelu_f(a));
            }
            __syncthreads();
#pragma unroll 4
            for (int cl = 0; cl < 32; ++cl) {
                const float* r2r = &R2W[(c0 + cl) * 9];
#pragma unroll
                for (int ky = 0; ky < 3; ++ky)
#pragma unroll
                for (int kx = 0; kx < 3; ++kx) {
                    const int y2 = py + ky - 1, x2 = pxx + kx - 1;
                    if (y2 >= 0 && y2 < 16 && x2 >= 0 && x2 < 16)
                        racc += bf2f(R1S[cl * 264 + y2 * 16 + x2]) * r2r[ky * 3 + kx];
                }
            }
            __syncthreads();
        }
        const float resv = tanhf(racc + R2B[0]) * 0.1f;
        const float pred = fminf(fmaxf(WARP[tid] + resv, 0.f), 1.f);
        out[((size_t)b * NSTEP + t) * 256 + tid] = pred;
        __syncthreads();   // scratch safe for next step
    }
}

// -------------------------------------------------------------- launch ----
extern "C" void kernel_launch(void* const* d_in, const int* in_sizes, int n_in,
                              void* d_out, int out_size, void* d_ws, size_t ws_size,
                              hipStream_t stream)
{
    const float* frames = (const float*)d_in[0];
    const float* e1w = (const float*)d_in[1];
    const float* e1b = (const float*)d_in[2];
    const float* e2w = (const float*)d_in[3];
    const float* e2b = (const float*)d_in[4];
    const float* slot_mu = (const float*)d_in[5];
    const float* tsw = (const float*)d_in[6];
    const float* tsb = (const float*)d_in[7];
    const float* qw = (const float*)d_in[8];
    const float* kw = (const float*)d_in[9];
    const float* vw = (const float*)d_in[10];
    const float* wih = (const float*)d_in[11];
    const float* whh = (const float*)d_in[12];
    const float* bih = (const float*)d_in[13];
    const float* bhh = (const float*)d_in[14];
    const float* m1w = (const float*)d_in[15];
    const float* m1b = (const float*)d_in[16];
    const float* m2w = (const float*)d_in[17];
    const float* m2b = (const float*)d_in[18];
    const float* maskw = (const float*)d_in[19];
    const float* maskb = (const float*)d_in[20];
    const float* upw = (const float*)d_in[21];
    const float* upb = (const float*)d_in[22];
    const float* r1w = (const float*)d_in[23];
    const float* r1b = (const float*)d_in[24];
    const float* r2w = (const float*)d_in[25];
    const float* r2b = (const float*)d_in[26];

    float* ws = (float*)d_ws;
    float* rmw  = ws + 0;
    float* rmb  = ws + 2048;
    float* kbf  = ws + 2064;
    float* vbf  = ws + 2192;
    short* w2bf  = (short*)(ws + 2320);
    short* wihbf = (short*)(ws + 133392);
    short* whhbf = (short*)(ws + 157968);
    short* qwbf  = (short*)(ws + 182544);
    short* kwf   = (short*)(ws + 190736);
    short* vwf   = (short*)(ws + 198928);

    hipLaunchKernelGGL(init_kernel, dim3(512), dim3(256), 0, stream,
                       maskw, maskb, e2w, wih, whh, qw, tsw, tsb, kw, vw,
                       rmw, rmb, kbf, vbf, w2bf, wihbf, whhbf, qwbf, kwf, vwf);
    hipLaunchKernelGGL(fused_all_kernel, dim3(512), dim3(256), 0, stream,
                       frames, w2bf, e1w, e1b, e2b, slot_mu,
                       kwf, vwf, kbf, vbf, qwbf, wihbf, whhbf, bih, bhh,
                       m1w, m1b, m2w, m2b, upw, upb,
                       r1w, r1b, r2w, r2b, rmw, rmb,
                       (float*)d_out);
}